// Round 2
// baseline (103.167 us; speedup 1.0000x reference)
//
#include <hip/hip_runtime.h>
#include <hip/hip_bf16.h>

#define B_ 256
#define T_ 1024
#define F_ 18
#define U_ 32
#define N_ 1000

__device__ __forceinline__ float fast_rcp(float v) { return __builtin_amdgcn_rcpf(v); }

// Key insight: state of id n evolves ONLY through timesteps with ids[b,t]==n.
// Output depends only on the final state of id_last = ids[b,T-1], i.e. on the
// ~2 timesteps (avg) in its chain. One block (1 wave64) per batch row:
//   1) ballot-scan ids row -> ordered list of t with ids[b,t]==id_last
//   2) run GRU step only on those timesteps (lanes 0-31: z cols + h~ cols,
//      lanes 32-63: r cols; r*h broadcast via constant-lane readlane)
//   3) MLP head -> out[b]
__global__ __launch_bounds__(64, 1) void gru_chain_kernel(
    const float* __restrict__ x, const int* __restrict__ ids,
    const float* __restrict__ table, const float* __restrict__ kernel_,
    const float* __restrict__ rkernel, const float* __restrict__ bias,
    const float* __restrict__ w1, const float* __restrict__ b1,
    const float* __restrict__ w2, const float* __restrict__ b2,
    float* __restrict__ out)
{
    __shared__ int   tlist[T_];
    __shared__ float hsh[U_];

    const int b   = blockIdx.x;
    const int tid = threadIdx.x;
    const int lo  = tid & 31;
    const int hf  = tid >> 5;    // 0: z-half, 1: r-half

    const int* idrow = ids + b * T_;
    const int  id_last = idrow[T_ - 1];

    // ---- per-lane weights in registers (issued early; latency overlaps scan) ----
    float wzr[U_], wh[U_];
    #pragma unroll
    for (int k = 0; k < U_; ++k) {
        wzr[k] = rkernel[k * 96 + hf * 32 + lo];   // rk_z (half0) / rk_r (half1)
        wh[k]  = rkernel[k * 96 + 64 + lo];        // rk_h
    }
    float kzr[F_], kh[F_];
    #pragma unroll
    for (int k = 0; k < F_; ++k) {
        kzr[k] = kernel_[k * 96 + hf * 32 + lo];
        kh[k]  = kernel_[k * 96 + 64 + lo];
    }
    const float bzr = bias[hf * 32 + lo];
    const float bh  = bias[64 + lo];

    // ---- initial state of id_last's chain ----
    if (hf == 0) hsh[lo] = table[(size_t)id_last * (B_ * U_) + b * U_ + lo];

    // ---- ballot-scan the ids row for matches, in timestep order ----
    int base = 0;
    #pragma unroll 4
    for (int c = 0; c < T_ / 64; ++c) {
        const int t = c * 64 + tid;
        const int v = idrow[t];
        const unsigned long long m = __ballot(v == id_last);
        if (v == id_last) {
            const int pos = base + __popcll(m & ((1ull << tid) - 1ull));
            tlist[pos] = t;
        }
        base += __popcll(m);   // wave-uniform
    }
    __syncthreads();

    // ---- GRU steps over the chain (avg ~2 iterations) ----
    for (int s = 0; s < base; ++s) {
        const int t = tlist[s];
        const float* xr = x + ((size_t)b * T_ + t) * F_;
        float xb[F_];
        xb[0] = (float)id_last;                    // inp[:,:,0] = ids (match => id_last)
        #pragma unroll
        for (int k = 1; k < F_; ++k) xb[k] = xr[k];

        float hb[U_];
        #pragma unroll
        for (int k = 0; k < U_; ++k) hb[k] = hsh[k];   // uniform -> LDS broadcast
        const float h_lo = hsh[lo];

        // x projection (z|r column on this lane, plus h~ column)
        float xzr = bzr, xh = bh;
        #pragma unroll
        for (int k = 0; k < F_; ++k) {
            xzr = fmaf(xb[k], kzr[k], xzr);
            xh  = fmaf(xb[k], kh[k],  xh);
        }

        // h @ rk_{z|r}  (4-way ILP split of the 32-FMA reduction)
        float a0 = 0.f, a1 = 0.f, a2 = 0.f, a3 = 0.f;
        #pragma unroll
        for (int k = 0; k < U_; k += 4) {
            a0 = fmaf(hb[k+0], wzr[k+0], a0);
            a1 = fmaf(hb[k+1], wzr[k+1], a1);
            a2 = fmaf(hb[k+2], wzr[k+2], a2);
            a3 = fmaf(hb[k+3], wzr[k+3], a3);
        }
        const float azr = xzr + ((a0 + a1) + (a2 + a3));
        const float zr  = fminf(fmaxf(fmaf(azr, 0.2f, 0.5f), 0.0f), 1.0f);
        const float gh  = zr * h_lo;   // half0: z*h, half1: r*h

        // broadcast (r*h) from lanes 32..63 via constant-lane readlane
        float rhb[U_];
        #pragma unroll
        for (int k = 0; k < U_; ++k)
            rhb[k] = __uint_as_float(
                __builtin_amdgcn_readlane(__float_as_uint(gh), 32 + k));

        // (r*h) @ rk_h
        float c0 = 0.f, c1 = 0.f, c2 = 0.f, c3 = 0.f;
        #pragma unroll
        for (int k = 0; k < U_; k += 4) {
            c0 = fmaf(rhb[k+0], wh[k+0], c0);
            c1 = fmaf(rhb[k+1], wh[k+1], c1);
            c2 = fmaf(rhb[k+2], wh[k+2], c2);
            c3 = fmaf(rhb[k+3], wh[k+3], c3);
        }
        const float ah = xh + ((c0 + c1) + (c2 + c3));
        // tanh(a) = 1 - 2/(e^{2a}+1) ; inf-safe at both tails
        const float e2 = __expf(2.0f * ah);
        const float hh = 1.0f - 2.0f * fast_rcp(e2 + 1.0f);
        const float hn = fmaf(1.0f - zr, hh, gh);  // z*h + (1-z)*h~

        if (hf == 0) hsh[lo] = hn;
        __syncthreads();
    }

    // ---- final MLP head: out[b] = sigmoid(relu(h_last@w1+b1)@w2 + b2) ----
    float hb[U_];
    #pragma unroll
    for (int k = 0; k < U_; ++k) hb[k] = hsh[k];
    float dacc = b1[lo];
    #pragma unroll
    for (int k = 0; k < U_; ++k) dacc = fmaf(hb[k], w1[k * 32 + lo], dacc);
    const float dv = fmaxf(dacc, 0.0f);
    float p = (hf == 0) ? dv * w2[lo] : 0.0f;
    #pragma unroll
    for (int off = 32; off >= 1; off >>= 1) p += __shfl_xor(p, off, 64);
    if (tid == 0) out[b] = fast_rcp(1.0f + __expf(-(p + b2[0])));
}

extern "C" void kernel_launch(void* const* d_in, const int* in_sizes, int n_in,
                              void* d_out, int out_size, void* d_ws, size_t ws_size,
                              hipStream_t stream) {
    const float* x       = (const float*)d_in[0];
    const int*   ids     = (const int*)d_in[1];
    const float* table   = (const float*)d_in[2];
    const float* kernel_ = (const float*)d_in[3];
    const float* rkernel = (const float*)d_in[4];
    const float* bias    = (const float*)d_in[5];
    const float* w1      = (const float*)d_in[6];
    const float* b1      = (const float*)d_in[7];
    const float* w2      = (const float*)d_in[8];
    const float* b2      = (const float*)d_in[9];
    float*       out     = (float*)d_out;

    hipLaunchKernelGGL(gru_chain_kernel, dim3(B_), dim3(64), 0, stream,
                       x, ids, table, kernel_, rkernel, bias, w1, b1, w2, b2, out);
}